// Round 5
// baseline (50969.934 us; speedup 1.0000x reference)
//
#include <hip/hip_runtime.h>
#include <math.h>

// ---------------------------------------------------------------------------
// DefaultHumanoidGRUCritic on MI355X — round 15
//
// Closed questions: 64 WG is the comm-geometry optimum (32->flat comm,
// 128->FETCH +64% and slower). Producer publish must be fire-and-forget
// (r14's s_waitcnt drain is wave-scalar -> stalls whole wave). Staging LDS
// writes must be stride-8B (r14's 16B-stride pattern: 6.7e7 conflicts).
// r10 floor = comm 1.1us + compute 0.49us SERIALIZED on the same lanes.
// Round-15: WAVE SPECIALIZATION — disjoint staging and compute waves so
// staging(k+1) overlaps compute(k); per-iter -> ~max(discover, compute):
//   * 64 WG x 640 thr (10 waves, 1 WG/CU via 96KB pad):
//     waves 0-3 staging (tid<128: ring0, 2 probes; tid 128-255: ring1, 2);
//     waves 4-5 roleA (r10-verbatim, 8 el x 16 lanes, W[24] from w_hh0);
//     waves 6-9 roleB (r10-verbatim, 8 el x 32 lanes, ih|hh halves).
//   * parity double-buffer: staging fills hbuf[p^1] while compute reads
//     hbuf[p]; ONE barrier/iter. Skew <=1 round (WG at k requires all
//     published k-1), 16-slot rings safe.
//   * protocol r10-exact: AGENT atomic 8B publish (NO drain), sc0 sc1
//     forced-miss 16B tag-verified loads, single-probe sleep(1) poll,
//     fail-fast POLL_LIM+abort (r12/r13-proven), DPP rotate-reduce
//     (r13/r14-proven, better absmax).
// ---------------------------------------------------------------------------

#define T_STEPS 16384
#define IN_DIM 341
#define HID 512
#define G3 1536
#define TTILE 16
#define NWG 64
#define RMASK 15
#define POLL_LIM (1<<18)

typedef unsigned int v4u __attribute__((ext_vector_type(4)));

__device__ __forceinline__ float dot4(float4 a, float4 b) {
  return fmaf(a.x, b.x, fmaf(a.y, b.y, fmaf(a.z, b.z, a.w * b.w)));
}
__device__ __forceinline__ float fast_sigmoid(float x) {
  return __builtin_amdgcn_rcpf(1.0f + __expf(-x));
}
__device__ __forceinline__ float fast_tanh(float x) {
  return fmaf(-2.0f, __builtin_amdgcn_rcpf(1.0f + __expf(2.0f * x)), 1.0f);
}
__device__ __forceinline__ void st_rlx64(unsigned long long* p, unsigned long long v) {
  __hip_atomic_store(p, v, __ATOMIC_RELAXED, __HIP_MEMORY_SCOPE_AGENT);
}
__device__ __forceinline__ unsigned long long pack_tv(unsigned tag, float v) {
  return ((unsigned long long)tag << 32) | (unsigned long long)__float_as_uint(v);
}
__device__ __forceinline__ void pin4(float4& v) {
  asm volatile("" : "+v"(v.x), "+v"(v.y), "+v"(v.z), "+v"(v.w));
}
// full-16-row sum via DPP rotate-accumulate (VALU, not DS pipe). proven r13/r14.
template <int CTRL>
__device__ __forceinline__ float ror_add(float x) {
  int t = __builtin_amdgcn_update_dpp(0, __float_as_int(x), CTRL, 0xf, 0xf, true);
  return x + __int_as_float(t);
}
__device__ __forceinline__ void reduce16x3(float& pr, float& pz, float& pn) {
  pr = ror_add<0x128>(pr); pz = ror_add<0x128>(pz); pn = ror_add<0x128>(pn);
  pr = ror_add<0x124>(pr); pz = ror_add<0x124>(pz); pn = ror_add<0x124>(pn);
  pr = ror_add<0x122>(pr); pz = ror_add<0x122>(pz); pn = ror_add<0x122>(pn);
  pr = ror_add<0x121>(pr); pz = ror_add<0x121>(pz); pn = ror_add<0x121>(pn);
}
// coherence-point 16B load (r10-proven): two (val,tag) pairs; sc0 sc1 forces
// the miss to the chip-level coherence point.
__device__ __forceinline__ v4u ld16(const unsigned long long* p) {
  v4u r;
  asm volatile("global_load_dwordx4 %0, %1, off sc0 sc1\n\ts_waitcnt vmcnt(0)"
               : "=v"(r) : "v"(p) : "memory");
  return r;
}
__device__ __forceinline__ void ld16x2(const unsigned long long* p0,
                                       const unsigned long long* p1,
                                       v4u& a, v4u& b) {
  asm volatile("global_load_dwordx4 %0, %2, off sc0 sc1\n\t"
               "global_load_dwordx4 %1, %3, off sc0 sc1\n\t"
               "s_waitcnt vmcnt(0)"
               : "=&v"(a), "=&v"(b) : "v"(p0), "v"(p1) : "memory");
}
__device__ __forceinline__ void set_abort(int* c) {
  if (c) __hip_atomic_store(c, 1, __ATOMIC_RELAXED, __HIP_MEMORY_SCOPE_AGENT);
}
__device__ __forceinline__ bool chk_abort(const int* c) {
  return c && __hip_atomic_load(c, __ATOMIC_RELAXED, __HIP_MEMORY_SCOPE_AGENT);
}
// r10-exact spin (single probe + sleep(1)) with r12-proven fail-fast.
__device__ __forceinline__ bool wait_tag(const unsigned long long* p, unsigned tag,
                                         v4u& a, int* ctrl) {
  if (a.y == tag && a.w == tag) return true;
  int gd = 0;
  for (;;) {
    __builtin_amdgcn_s_sleep(1);
    a = ld16(p);
    if (a.y == tag && a.w == tag) return true;
    if (++gd >= POLL_LIM) { set_abort(ctrl); return false; }
    if ((gd & 255) == 0 && chk_abort(ctrl)) return false;
  }
}

// ---- k0: concat observations ----------------------------------------------
__global__ __launch_bounds__(384) void concat_kernel(
    const float* __restrict__ p0, const float* __restrict__ p1,
    const float* __restrict__ p2, const float* __restrict__ p3,
    const float* __restrict__ p4, const float* __restrict__ p5,
    const float* __restrict__ p6, const float* __restrict__ p7,
    const float* __restrict__ p8, const float* __restrict__ p9,
    const float* __restrict__ p10, const float* __restrict__ p11,
    const float* __restrict__ p12, float* __restrict__ obs) {
  int t = blockIdx.x;
  int k = threadIdx.x;
  if (k >= IN_DIM) return;
  float v;
  if (k < 21)       v = p0[t*21 + k];
  else if (k < 42)  v = p1[t*21 + (k-21)];
  else if (k < 202) v = p2[t*160 + (k-42)];
  else if (k < 298) v = p3[t*96 + (k-202)];
  else if (k < 301) v = p4[t*3 + (k-298)];
  else if (k < 304) v = p5[t*3 + (k-301)];
  else if (k < 325) v = p6[t*21 + (k-304)];
  else if (k < 328) v = p7[t*3 + (k-325)];
  else if (k < 332) v = p8[t*4 + (k-328)];
  else if (k < 335) v = p9[t*3 + (k-332)];
  else if (k < 338) v = p10[t*3 + (k-335)];
  else if (k < 340) v = p11[t*2 + (k-338)];
  else              v = p12[t];
  obs[(size_t)t*IN_DIM + k] = v;
}

// ---- k1: transpose w_ih0 ---------------------------------------------------
__global__ __launch_bounds__(256) void transpose_kernel(const float* __restrict__ w,
                                                        float* __restrict__ wT) {
  __shared__ float tile[32][33];
  int tx = threadIdx.x;  // 32
  int ty = threadIdx.y;  // 8
  int k = blockIdx.x*32 + tx;
#pragma unroll
  for (int jj = 0; jj < 4; jj++) {
    int r = blockIdx.y*32 + ty*4 + jj;
    tile[ty*4+jj][tx] = (k < IN_DIM) ? w[(size_t)r*IN_DIM + k] : 0.f;
  }
  __syncthreads();
#pragma unroll
  for (int jj = 0; jj < 4; jj++) {
    int kk = blockIdx.x*32 + ty*4 + jj;
    if (kk < IN_DIM) wT[(size_t)kk*G3 + blockIdx.y*32 + tx] = tile[tx][ty*4+jj];
  }
}

// ---- k2: IG0 = obs @ w_ih0^T + b_ih0 --------------------------------------
__global__ __launch_bounds__(256) void ig0_kernel(const float* __restrict__ wT,
                                                  const float* __restrict__ obs,
                                                  const float* __restrict__ b_ih0,
                                                  float* __restrict__ ig0) {
  int o = blockIdx.x*256 + threadIdx.x;
  int t0 = blockIdx.y * TTILE;
  float acc[TTILE];
  float b = b_ih0[o];
#pragma unroll
  for (int tt = 0; tt < TTILE; tt++) acc[tt] = b;
  for (int k = 0; k < IN_DIM; k++) {
    float wv = wT[(size_t)k*G3 + o];
#pragma unroll
    for (int tt = 0; tt < TTILE; tt++)
      acc[tt] = fmaf(obs[(size_t)(t0+tt)*IN_DIM + k], wv, acc[tt]);
  }
#pragma unroll
  for (int tt = 0; tt < TTILE; tt++)
    ig0[(size_t)(t0+tt)*G3 + o] = acc[tt];
}

// ---- k_init: seed ring slot 0 with tagged initial hidden; clear abort ------
__global__ __launch_bounds__(512) void init_kernel(const float* __restrict__ hid,
                                                   unsigned long long* ring0,
                                                   unsigned long long* ring1,
                                                   int* ctrl) {
  int e = threadIdx.x;
  if (e == 0 && ctrl)
    __hip_atomic_store(ctrl, 0, __ATOMIC_RELAXED, __HIP_MEMORY_SCOPE_AGENT);
  st_rlx64(&ring0[e], pack_tv(0u, hid[e]));
  st_rlx64(&ring1[e], pack_tv(0u, hid[HID + e]));
}

// ---- k3: fused sequential GRU scan (wave-specialized) ----------------------
// 64 WGs x 640 threads (10 waves), 1 WG/CU via 96KB pad.
//   waves 0-3 (tid<256): STAGING — tid<128 ring0 (pairs tid, tid+128),
//     tid 128-255 ring1. Round k stages hbuf[p^1] for round k+1:
//     ring0 slot (k+1)&15 tag k+1 (=h0[k]) and ring1 slot k&15 tag k
//     (=h1[k-1]) — both published DURING round k by compute waves of all
//     WGs, discovered concurrently (the overlap).
//   waves 4-5 (tid 256-383): roleA — h0[k] = GRU0(hbuf0[p], igbuf[p]),
//     publish ring0 slot (k+1)&15 tag k+1 (fire-and-forget).
//   waves 6-9 (tid 384-639): roleB — h1[k-1] = GRU1(hbuf0[p], hbuf1[p]),
//     publish ring1 slot k&15 tag k + h1a store.
// One barrier/iter. h^(t) at slot (t+1)&15 tag t+1; seed slot 0 tag 0.
__global__ __launch_bounds__(640)
void seq_kernel(
    const float* __restrict__ ig0, const float* __restrict__ w_hh0,
    const float* __restrict__ b_n0, const float* __restrict__ w_ih1,
    const float* __restrict__ w_hh1, const float* __restrict__ b_ih1,
    const float* __restrict__ b_n1,
    unsigned long long* ring0, unsigned long long* ring1,
    float* __restrict__ h1a, float* __restrict__ d_out, int* ctrl) {
  __shared__ float hbuf0[2][HID];
  __shared__ float hbuf1[2][HID];
  __shared__ float igbuf[2][24];
  __shared__ float vpad[24576];   // 96KB: LDS occupancy -> 1 WG/CU
  __shared__ int s_dead;
  const int tid = threadIdx.x;
  const int wg = blockIdx.x;
  if (tid == 0) s_dead = 0;
  if (d_out == nullptr) {         // never true; defeats LDS elision
    vpad[tid] = (float)tid;
    __syncthreads();
    h1a[tid] = vpad[639 - tid];
  }
  __syncthreads();                // covers s_dead init

  const bool stg   = (tid < 256);
  const bool roleA = (tid >= 256) && (tid < 384);
  const int a  = tid - 256;                // roleA lane 0..127
  const int u  = tid - 384;                // roleB lane 0..255
  const int g  = roleA ? (a >> 4) : (u >> 5);
  const int jj = roleA ? (a & 15) : (u & 15);
  const int half = roleA ? 0 : ((u >> 4) & 1);   // B: 0=ih(h0), 1=hh(h1)
  const int j32 = u & 31;
  const int eg = wg*8 + g;
  const bool leadA = roleA && (jj == 0);
  const bool leadB = (!stg) && (!roleA) && (j32 == 0);

  // compute lanes: 24 float4 (96 floats) of weights, loaded once, PINNED.
  float4 W[24];
  float cr=0.f, cz=0.f, cn=0.f, bnl=0.f;
  if (!stg) {
    const float* wsrc = roleA ? w_hh0 : (half ? w_hh1 : w_ih1);
#pragma unroll
    for (int gate = 0; gate < 3; gate++) {
      const float4* row = (const float4*)(wsrc + (size_t)(gate*HID + eg)*HID);
#pragma unroll
      for (int i = 0; i < 8; i++) {
        W[gate*8+i] = row[jj + 16*i];
        pin4(W[gate*8+i]);
      }
    }
    if (roleA) {
      bnl = b_n0[eg];
    } else {
      cr = b_ih1[eg]; cz = b_ih1[512+eg]; cn = b_ih1[1024+eg]; bnl = b_n1[eg];
    }
  }

  // ---- prologue: stage hbuf0[0] (ring0 slot 0 tag 0) + igbuf[0] ----
  if (tid < 128) {
    const unsigned long long* pa  = ring0 + 2*tid;
    const unsigned long long* pa2 = pa + 256;
    v4u x, y;
    ld16x2(pa, pa2, x, y);
    bool o1 = wait_tag(pa,  0u, x, ctrl);
    bool o2 = wait_tag(pa2, 0u, y, ctrl);
    if (!(o1 && o2)) s_dead = 1;
    ((float2*)hbuf0[0])[tid] =
        make_float2(__uint_as_float(x.x), __uint_as_float(x.z));
    ((float2*)hbuf0[0])[tid+128] =
        make_float2(__uint_as_float(y.x), __uint_as_float(y.z));
  }
  if (tid < 24) igbuf[0][tid] = ig0[(size_t)(tid>>3)*HID + wg*8 + (tid&7)];
  __syncthreads();
  if (s_dead) return;

  for (int k = 0; k <= T_STEPS; k++) {
    const int p = k & 1;
    bool ok = true;
    if (stg) {
      if (k < T_STEPS) {
        // ig prefetch for round k+1: issue early, write late
        float igpre = 0.f;
        if (tid < 24) {
          int kk = (k+1 < T_STEPS) ? (k+1) : (T_STEPS-1);
          igpre = ig0[(size_t)kk*G3 + (size_t)(tid>>3)*HID + wg*8 + (tid&7)];
        }
        if (tid < 128) {
          // ring0 slot (k+1)&15 tag k+1 = h0[k], published during this round
          const unsigned long long* pa  =
              ring0 + (size_t)((k+1) & RMASK)*HID + 2*tid;
          const unsigned long long* pa2 = pa + 256;
          v4u x, y;
          ld16x2(pa, pa2, x, y);
          bool o1 = wait_tag(pa,  (unsigned)(k+1), x, ctrl);
          bool o2 = wait_tag(pa2, (unsigned)(k+1), y, ctrl);
          ok = o1 && o2;
          ((float2*)hbuf0[p^1])[tid] =
              make_float2(__uint_as_float(x.x), __uint_as_float(x.z));
          ((float2*)hbuf0[p^1])[tid+128] =
              make_float2(__uint_as_float(y.x), __uint_as_float(y.z));
        } else {
          // ring1 slot k&15 tag k = h1[k-1], published during this round
          const int s2 = tid - 128;
          const unsigned long long* pb  =
              ring1 + (size_t)(k & RMASK)*HID + 2*s2;
          const unsigned long long* pb2 = pb + 256;
          v4u x, y;
          ld16x2(pb, pb2, x, y);
          bool o1 = wait_tag(pb,  (unsigned)k, x, ctrl);
          bool o2 = wait_tag(pb2, (unsigned)k, y, ctrl);
          ok = o1 && o2;
          ((float2*)hbuf1[p^1])[s2] =
              make_float2(__uint_as_float(x.x), __uint_as_float(x.z));
          ((float2*)hbuf1[p^1])[s2+128] =
              make_float2(__uint_as_float(y.x), __uint_as_float(y.z));
        }
        if (tid < 24) igbuf[p ^ 1][tid] = igpre;
      }
    } else {
      // ---- compute waves: read hbuf[p]/igbuf[p], publish fire-and-forget --
      const bool act = roleA ? (k < T_STEPS) : (k >= 1);
      if (act) {
        const float4* hp = (roleA || half == 0) ? (const float4*)hbuf0[p]
                                                : (const float4*)hbuf1[p];
        float pr=0.f, pz=0.f, pn=0.f;
#pragma unroll
        for (int i = 0; i < 8; i++) {
          float4 hv = hp[jj + 16*i];   // <=2-way bank alias: free (r10 PMC=0)
          pr += dot4(W[i],hv); pz += dot4(W[8+i],hv); pn += dot4(W[16+i],hv);
        }
        reduce16x3(pr, pz, pn);        // DPP row_ror: full sum in every lane
        if (roleA) {
          if (leadA) {
            float r = fast_sigmoid(igbuf[p][g] + pr);
            float z = fast_sigmoid(igbuf[p][8+g] + pz);
            float n = fast_tanh(igbuf[p][16+g] + r*(pn + bnl));
            float hnew = n + z*(hbuf0[p][eg] - n);
            st_rlx64(&ring0[(size_t)((k+1) & RMASK)*HID + eg],
                     pack_tv((unsigned)(k+1), hnew));
            if (k == T_STEPS-1) d_out[T_STEPS + eg] = hnew;
          }
        } else {
          // harvest hh-half sums (lane 16 of the 32-lane group)
          float qr = __shfl(pr, 16, 32);
          float qz = __shfl(pz, 16, 32);
          float qn = __shfl(pn, 16, 32);
          if (leadB) {
            float r = fast_sigmoid(pr + cr + qr);
            float z = fast_sigmoid(pz + cz + qz);
            float n = fast_tanh(pn + cn + r*(qn + bnl));
            float hnew = n + z*(hbuf1[p][eg] - n);
            st_rlx64(&ring1[(size_t)(k & RMASK)*HID + eg],
                     pack_tv((unsigned)k, hnew));
            h1a[(size_t)(k-1)*HID + eg] = hnew;   // plain store for the MLP
            if (k == T_STEPS) d_out[T_STEPS + HID + eg] = hnew;
          }
        }
      }
    }
    if (!ok) s_dead = 1;          // pre-barrier write; benign race
    __syncthreads();              // the only barrier per iteration
    if (s_dead) break;            // uniform post-barrier read
  }
}

// ---- k4: batched MLP head --------------------------------------------------
__global__ __launch_bounds__(64) void mlp_kernel(
    const float* __restrict__ h1_all, const float* __restrict__ mw0,
    const float* __restrict__ mb0, const float* __restrict__ mw1,
    const float* __restrict__ mb1, const float* __restrict__ mw2,
    const float* __restrict__ mb2, float* __restrict__ out) {
  const int l = threadIdx.x;
  const int t0 = blockIdx.x * 8;
  __shared__ float v0s[8][64];
  float acc[8];
#pragma unroll
  for (int tt = 0; tt < 8; tt++) acc[tt] = mb0[l];
  const float4* w = (const float4*)(mw0 + (size_t)l*512);
#pragma unroll 4
  for (int i = 0; i < 128; i++) {
    float4 a = w[i];
#pragma unroll
    for (int tt = 0; tt < 8; tt++) {
      float4 b = ((const float4*)(h1_all + (size_t)(t0+tt)*512))[i];
      acc[tt] = fmaf(a.x,b.x, fmaf(a.y,b.y, fmaf(a.z,b.z, fmaf(a.w,b.w, acc[tt]))));
    }
  }
#pragma unroll
  for (int tt = 0; tt < 8; tt++) v0s[tt][l] = fmaxf(acc[tt], 0.f);
  __syncthreads();
  float acc1[8];
#pragma unroll
  for (int tt = 0; tt < 8; tt++) acc1[tt] = mb1[l];
  const float* w1 = mw1 + (size_t)l*64;
  for (int jj = 0; jj < 64; jj++) {
    float wv = w1[jj];
#pragma unroll
    for (int tt = 0; tt < 8; tt++) acc1[tt] = fmaf(wv, v0s[tt][jj], acc1[tt]);
  }
  float w2 = mw2[l];
  float bb = mb2[0];
#pragma unroll
  for (int tt = 0; tt < 8; tt++) {
    float y = w2 * fmaxf(acc1[tt], 0.f);
#pragma unroll
    for (int s = 32; s > 0; s >>= 1) y += __shfl_down(y, s, 64);
    if (l == 0) out[t0+tt] = y + bb;
  }
}

// ---------------------------------------------------------------------------
extern "C" void kernel_launch(void* const* d_in, const int* in_sizes, int n_in,
                              void* d_out, int out_size, void* d_ws, size_t ws_size,
                              hipStream_t stream) {
  const float* p0  = (const float*)d_in[0];
  const float* p1  = (const float*)d_in[1];
  const float* p2  = (const float*)d_in[2];
  const float* p3  = (const float*)d_in[3];
  const float* p4  = (const float*)d_in[4];
  const float* p5  = (const float*)d_in[5];
  const float* p6  = (const float*)d_in[6];
  const float* p7  = (const float*)d_in[7];
  const float* p8  = (const float*)d_in[8];
  const float* p9  = (const float*)d_in[9];
  const float* p10 = (const float*)d_in[10];
  const float* p11 = (const float*)d_in[11];
  const float* p12 = (const float*)d_in[12];
  const float* hid   = (const float*)d_in[13];
  const float* w_ih0 = (const float*)d_in[14];
  const float* w_hh0 = (const float*)d_in[15];
  const float* b_ih0 = (const float*)d_in[16];
  const float* b_n0  = (const float*)d_in[17];
  const float* w_ih1 = (const float*)d_in[18];
  const float* w_hh1 = (const float*)d_in[19];
  const float* b_ih1 = (const float*)d_in[20];
  const float* b_n1  = (const float*)d_in[21];
  const float* mw0 = (const float*)d_in[22];
  const float* mb0 = (const float*)d_in[23];
  const float* mw1 = (const float*)d_in[24];
  const float* mb1 = (const float*)d_in[25];
  const float* mw2 = (const float*)d_in[26];
  const float* mb2 = (const float*)d_in[27];
  float* out = (float*)d_out;

  // workspace: ig0 | ring0 | ring1 | h1a | [ctrl]  (obs/wT alias h1a region)
  char* base = (char*)d_ws;
  const size_t IG0_B = (size_t)T_STEPS*G3*4;     // 100,663,296
  const size_t R0_B  = (size_t)16*HID*8;         //      65,536
  const size_t R1_B  = (size_t)16*HID*8;         //      65,536
  const size_t H1A_B = (size_t)T_STEPS*HID*4;    //  33,554,432
  const size_t TOTAL = IG0_B + R0_B + R1_B + H1A_B;
  float* ig0 = (float*)base;
  unsigned long long* ring0 = (unsigned long long*)(base + IG0_B);
  unsigned long long* ring1 = (unsigned long long*)(base + IG0_B + R0_B);
  float* h1a = (float*)(base + IG0_B + R0_B + R1_B);
  float* obs = h1a;                                              // alias
  float* wT  = (float*)((char*)h1a + (size_t)T_STEPS*IN_DIM*4);  // alias
  if (ws_size < TOTAL) return;
  int* ctrl = (ws_size >= TOTAL + 4096) ? (int*)(base + TOTAL) : nullptr;

  concat_kernel<<<T_STEPS, 384, 0, stream>>>(p0,p1,p2,p3,p4,p5,p6,p7,p8,p9,p10,p11,p12, obs);
  transpose_kernel<<<dim3(11,48), dim3(32,8), 0, stream>>>(w_ih0, wT);
  ig0_kernel<<<dim3(6, T_STEPS/TTILE), 256, 0, stream>>>(wT, obs, b_ih0, ig0);
  init_kernel<<<1, 512, 0, stream>>>(hid, ring0, ring1, ctrl);
  seq_kernel<<<NWG, 640, 0, stream>>>(ig0, w_hh0, b_n0, w_ih1, w_hh1, b_ih1, b_n1,
                                      ring0, ring1, h1a, out, ctrl);
  mlp_kernel<<<T_STEPS/8, 64, 0, stream>>>(h1a, mw0, mb0, mw1, mb1, mw2, mb2, out);
}

// Round 8
// 28938.547 us; speedup vs baseline: 1.7613x; 1.7613x over previous
//
#include <hip/hip_runtime.h>
#include <math.h>

// ---------------------------------------------------------------------------
// DefaultHumanoidGRUCritic on MI355X — round 17 (resubmit; r7 bench was an
// infra failure: "MI355X container failed twice" — kernel never measured)
//
// r16 post-mortem: split WG families have unbounded inter-family skew; once
// h0 runs >ring-depth ahead, tags are destroyed before h1 reads them ->
// abort -> wrong answer. Reverted. The ledger pins the irreducible loop at
// publish->discover (~1.1us) + roleA compute (~0.2us); r10's extra ~0.3-0.4us
// is (a) lanes 128-255 serializing TWO tag-waits and (b) 256 fresh-data
// pollers/WG where 128 suffice.
// Round-17 = r10 structure byte-for-byte EXCEPT staging assignment:
//   * lanes 0-127: ring0 slots {t, t+128}, tag k, joint spin (wait_tag2
//     probes both lines each sleep-round -> same-probe discovery). Also the
//     roleA compute lanes: the critical chain stages its own data.
//   * lanes 128-255: ring1 slots {u, u+128}, tag k-1 (stale by a round ->
//     near-instant). NO lane waits on both rings; ring0 pollers halved.
//   * lanes 256-383: no staging; barrier early; roleB tail hides in comm.
//   * LDS writes stride-8B (slot t / t+128) -> 2-way alias, free (r10 PMC=0).
//   * k=0: ring1 staging skipped (roleB inactive at k=0).
//   * keep: 16-slot rings, AGENT atomic fire-and-forget publish, sc0 sc1
//     forced-miss tag-verified loads, sleep(1) poll cadence, fail-fast
//     POLL_LIM+abort, DPP rotate-reduce, 96KB pad -> 1 WG/CU,
//     waves_per_eu(1,2), parity LDS double-buffer, ig0 prefetch (tid<24).
// Safety audit (hang-impossibility): every spin caps at POLL_LIM (~0.3s),
// aborts via workspace flag, exits through the uniform s_dead barrier path.
// Single family + 1 barrier/iter bounds inter-WG skew at 1 round << 16 slots.
// ---------------------------------------------------------------------------

#define T_STEPS 16384
#define IN_DIM 341
#define HID 512
#define G3 1536
#define TTILE 16
#define R0M 15
#define R1M 15
#define POLL_LIM (1<<18)

typedef unsigned int v4u __attribute__((ext_vector_type(4)));

__device__ __forceinline__ float dot4(float4 a, float4 b) {
  return fmaf(a.x, b.x, fmaf(a.y, b.y, fmaf(a.z, b.z, a.w * b.w)));
}
__device__ __forceinline__ float fast_sigmoid(float x) {
  return __builtin_amdgcn_rcpf(1.0f + __expf(-x));
}
__device__ __forceinline__ float fast_tanh(float x) {
  return fmaf(-2.0f, __builtin_amdgcn_rcpf(1.0f + __expf(2.0f * x)), 1.0f);
}
__device__ __forceinline__ void st_rlx64(unsigned long long* p, unsigned long long v) {
  __hip_atomic_store(p, v, __ATOMIC_RELAXED, __HIP_MEMORY_SCOPE_AGENT);
}
__device__ __forceinline__ unsigned long long pack_tv(unsigned tag, float v) {
  return ((unsigned long long)tag << 32) | (unsigned long long)__float_as_uint(v);
}
__device__ __forceinline__ void pin4(float4& v) {
  asm volatile("" : "+v"(v.x), "+v"(v.y), "+v"(v.z), "+v"(v.w));
}
// full-16-row sum via DPP rotate-accumulate (VALU). proven r13/r14.
template <int CTRL>
__device__ __forceinline__ float ror_add(float x) {
  int t = __builtin_amdgcn_update_dpp(0, __float_as_int(x), CTRL, 0xf, 0xf, true);
  return x + __int_as_float(t);
}
__device__ __forceinline__ void reduce16x3(float& pr, float& pz, float& pn) {
  pr = ror_add<0x128>(pr); pz = ror_add<0x128>(pz); pn = ror_add<0x128>(pn);
  pr = ror_add<0x124>(pr); pz = ror_add<0x124>(pz); pn = ror_add<0x124>(pn);
  pr = ror_add<0x122>(pr); pz = ror_add<0x122>(pz); pn = ror_add<0x122>(pn);
  pr = ror_add<0x121>(pr); pz = ror_add<0x121>(pz); pn = ror_add<0x121>(pn);
}
// coherence-point 16B load (r10-proven): two (val,tag) pairs; sc0 sc1 forces
// the miss to the chip-level coherence point.
__device__ __forceinline__ v4u ld16(const unsigned long long* p) {
  v4u r;
  asm volatile("global_load_dwordx4 %0, %1, off sc0 sc1\n\ts_waitcnt vmcnt(0)"
               : "=v"(r) : "v"(p) : "memory");
  return r;
}
__device__ __forceinline__ void ld16x2(const unsigned long long* p0,
                                       const unsigned long long* p1,
                                       v4u& a, v4u& b) {
  asm volatile("global_load_dwordx4 %0, %2, off sc0 sc1\n\t"
               "global_load_dwordx4 %1, %3, off sc0 sc1\n\t"
               "s_waitcnt vmcnt(0)"
               : "=&v"(a), "=&v"(b) : "v"(p0), "v"(p1) : "memory");
}
__device__ __forceinline__ void set_abort(int* c) {
  if (c) __hip_atomic_store(c, 1, __ATOMIC_RELAXED, __HIP_MEMORY_SCOPE_AGENT);
}
__device__ __forceinline__ bool chk_abort(const int* c) {
  return c && __hip_atomic_load(c, __ATOMIC_RELAXED, __HIP_MEMORY_SCOPE_AGENT);
}
// joint spin on TWO same-tag lines: r10 cadence (sleep(1) + probe) but both
// lines probed per round -> same-probe discovery, no serialized second wait.
__device__ __forceinline__ bool wait_tag2(const unsigned long long* p0,
                                          const unsigned long long* p1,
                                          unsigned tag, v4u& a, v4u& b,
                                          int* ctrl) {
  bool ma = (a.y == tag && a.w == tag);
  bool mb = (b.y == tag && b.w == tag);
  if (ma && mb) return true;
  int gd = 0;
  for (;;) {
    __builtin_amdgcn_s_sleep(1);
    if (!ma && !mb)      ld16x2(p0, p1, a, b);
    else if (!ma)        a = ld16(p0);
    else                 b = ld16(p1);
    ma = (a.y == tag && a.w == tag);
    mb = (b.y == tag && b.w == tag);
    if (ma && mb) return true;
    if (++gd >= POLL_LIM) { set_abort(ctrl); return false; }
    if ((gd & 255) == 0 && chk_abort(ctrl)) return false;
  }
}

// ---- k0: concat observations ----------------------------------------------
__global__ __launch_bounds__(384) void concat_kernel(
    const float* __restrict__ p0, const float* __restrict__ p1,
    const float* __restrict__ p2, const float* __restrict__ p3,
    const float* __restrict__ p4, const float* __restrict__ p5,
    const float* __restrict__ p6, const float* __restrict__ p7,
    const float* __restrict__ p8, const float* __restrict__ p9,
    const float* __restrict__ p10, const float* __restrict__ p11,
    const float* __restrict__ p12, float* __restrict__ obs) {
  int t = blockIdx.x;
  int k = threadIdx.x;
  if (k >= IN_DIM) return;
  float v;
  if (k < 21)       v = p0[t*21 + k];
  else if (k < 42)  v = p1[t*21 + (k-21)];
  else if (k < 202) v = p2[t*160 + (k-42)];
  else if (k < 298) v = p3[t*96 + (k-202)];
  else if (k < 301) v = p4[t*3 + (k-298)];
  else if (k < 304) v = p5[t*3 + (k-301)];
  else if (k < 325) v = p6[t*21 + (k-304)];
  else if (k < 328) v = p7[t*3 + (k-325)];
  else if (k < 332) v = p8[t*4 + (k-328)];
  else if (k < 335) v = p9[t*3 + (k-332)];
  else if (k < 338) v = p10[t*3 + (k-335)];
  else if (k < 340) v = p11[t*2 + (k-338)];
  else              v = p12[t];
  obs[(size_t)t*IN_DIM + k] = v;
}

// ---- k1: transpose w_ih0 ---------------------------------------------------
__global__ __launch_bounds__(256) void transpose_kernel(const float* __restrict__ w,
                                                        float* __restrict__ wT) {
  __shared__ float tile[32][33];
  int tx = threadIdx.x;  // 32
  int ty = threadIdx.y;  // 8
  int k = blockIdx.x*32 + tx;
#pragma unroll
  for (int jj = 0; jj < 4; jj++) {
    int r = blockIdx.y*32 + ty*4 + jj;
    tile[ty*4+jj][tx] = (k < IN_DIM) ? w[(size_t)r*IN_DIM + k] : 0.f;
  }
  __syncthreads();
#pragma unroll
  for (int jj = 0; jj < 4; jj++) {
    int kk = blockIdx.x*32 + ty*4 + jj;
    if (kk < IN_DIM) wT[(size_t)kk*G3 + blockIdx.y*32 + tx] = tile[tx][ty*4+jj];
  }
}

// ---- k2: IG0 = obs @ w_ih0^T + b_ih0 --------------------------------------
__global__ __launch_bounds__(256) void ig0_kernel(const float* __restrict__ wT,
                                                  const float* __restrict__ obs,
                                                  const float* __restrict__ b_ih0,
                                                  float* __restrict__ ig0) {
  int o = blockIdx.x*256 + threadIdx.x;
  int t0 = blockIdx.y * TTILE;
  float acc[TTILE];
  float b = b_ih0[o];
#pragma unroll
  for (int tt = 0; tt < TTILE; tt++) acc[tt] = b;
  for (int k = 0; k < IN_DIM; k++) {
    float wv = wT[(size_t)k*G3 + o];
#pragma unroll
    for (int tt = 0; tt < TTILE; tt++)
      acc[tt] = fmaf(obs[(size_t)(t0+tt)*IN_DIM + k], wv, acc[tt]);
  }
#pragma unroll
  for (int tt = 0; tt < TTILE; tt++)
    ig0[(size_t)(t0+tt)*G3 + o] = acc[tt];
}

// ---- k_init: seed ring slot 0 with tagged initial hidden; clear abort ------
__global__ __launch_bounds__(512) void init_kernel(const float* __restrict__ hid,
                                                   unsigned long long* ring0,
                                                   unsigned long long* ring1,
                                                   int* ctrl) {
  int e = threadIdx.x;
  if (e == 0 && ctrl)
    __hip_atomic_store(ctrl, 0, __ATOMIC_RELAXED, __HIP_MEMORY_SCOPE_AGENT);
  st_rlx64(&ring0[e], pack_tv(0u, hid[e]));
  st_rlx64(&ring1[e], pack_tv(0u, hid[HID + e]));
}

// ---- k3: fused sequential GRU scan ----------------------------------------
// 64 WGs x 384 threads, 1 WG/CU. Iteration k (k = 0..T inclusive):
//   stage h0[k-1] (ring0 slot k&15, tag k; lanes 0-127, slots {t,t+128}) and
//   h1[k-2] (ring1 slot (k-1)&15, tag k-1; lanes 128-255, slots {u,u+128},
//   skipped at k=0); barrier; compute h0[k] (roleA lanes 0-127, if k<T) and
//   h1[k-1] (roleB lanes 128-383, if k>=1); publish h0[k] -> ring0 slot
//   (k+1)&15 tag k+1, h1[k-1] -> ring1 slot k&15 tag k + h1a store.
// h^(t) lives at slot (t+1)&15 with tag t+1; seed at slot 0 tag 0.
__global__ __launch_bounds__(384)
__attribute__((amdgpu_waves_per_eu(1, 2)))
void seq_kernel(
    const float* __restrict__ ig0, const float* __restrict__ w_hh0,
    const float* __restrict__ b_n0, const float* __restrict__ w_ih1,
    const float* __restrict__ w_hh1, const float* __restrict__ b_ih1,
    const float* __restrict__ b_n1,
    unsigned long long* ring0, unsigned long long* ring1,
    float* __restrict__ h1a, float* __restrict__ d_out, int* ctrl) {
  __shared__ float hbuf0[2][HID];
  __shared__ float hbuf1[2][HID];
  __shared__ float igbuf[2][24];
  __shared__ float vpad[24576];   // 96KB: occupancy calc -> 1 WG/CU
  __shared__ int s_dead;
  const int tid = threadIdx.x;
  const int wg = blockIdx.x;
  if (tid == 0) s_dead = 0;
  if (d_out == nullptr) {         // never true; defeats LDS elision
    vpad[tid] = (float)tid;
    __syncthreads();
    h1a[tid] = vpad[383 - tid];
  }

  const bool roleA = (tid < 128);          // 8 h0 elements, 16 lanes each
  const int u = tid - 128;                 // role B: 8 h1 elements, 32 lanes
  const int g = roleA ? (tid >> 4) : (u >> 5);
  const int jj = roleA ? (tid & 15) : (u & 15);
  const int half = roleA ? 0 : ((u >> 4) & 1);   // B: 0=ih(h0), 1=hh(h1)
  const int j32 = roleA ? 0 : (u & 31);
  const int eg = wg*8 + g;
  const bool leadA = roleA && (jj == 0);
  const bool leadB = (!roleA) && (j32 == 0);

  // 24 float4 (96 floats) of weights per lane, loaded once, PINNED resident.
  const float* wsrc = roleA ? w_hh0 : (half ? w_hh1 : w_ih1);
  float4 W[24];
#pragma unroll
  for (int gate = 0; gate < 3; gate++) {
    const float4* row = (const float4*)(wsrc + (size_t)(gate*HID + eg)*HID);
#pragma unroll
    for (int i = 0; i < 8; i++) {
      W[gate*8+i] = row[jj + 16*i];
      pin4(W[gate*8+i]);
    }
  }
  float cr=0.f, cz=0.f, cn=0.f, bnl;
  if (roleA) {
    bnl = b_n0[eg];
  } else {
    cr = b_ih1[eg]; cz = b_ih1[512+eg]; cn = b_ih1[1024+eg]; bnl = b_n1[eg];
  }

  const int iggate = tid >> 3, ige = tid & 7;   // tid<24: ig prefetch lanes
  if (tid < 24) igbuf[0][tid] = ig0[(size_t)iggate*HID + wg*8 + ige];

  for (int k = 0; k <= T_STEPS; k++) {
    const int p = k & 1;
    // prefetch ig for h0[k+1] (plain cached load; LDS write after compute)
    float igpre = 0.f;
    if (tid < 24) {
      int kk = (k+1 < T_STEPS) ? (k+1) : (T_STEPS-1);
      igpre = ig0[(size_t)kk*G3 + (size_t)iggate*HID + wg*8 + ige];
    }
    // ---- staging: lanes 0-127 ring0 (tag k), lanes 128-255 ring1 (k-1) ----
    bool ok = true;
    if (tid < 128) {
      const unsigned long long* pa  = ring0 + (size_t)(k & R0M)*HID + 2*tid;
      const unsigned long long* pa2 = pa + 256;
      v4u a, a2;
      ld16x2(pa, pa2, a, a2);
      ok = wait_tag2(pa, pa2, (unsigned)k, a, a2, ctrl);
      ((float2*)hbuf0[p])[tid] =
          make_float2(__uint_as_float(a.x),  __uint_as_float(a.z));
      ((float2*)hbuf0[p])[tid+128] =
          make_float2(__uint_as_float(a2.x), __uint_as_float(a2.z));
    } else if (tid < 256 && k >= 1) {
      const int s1 = tid - 128;
      const unsigned long long* pb  = ring1 + (size_t)((k-1) & R1M)*HID + 2*s1;
      const unsigned long long* pb2 = pb + 256;
      v4u b, b2;
      ld16x2(pb, pb2, b, b2);
      ok = wait_tag2(pb, pb2, (unsigned)(k-1), b, b2, ctrl);
      ((float2*)hbuf1[p])[s1] =
          make_float2(__uint_as_float(b.x),  __uint_as_float(b.z));
      ((float2*)hbuf1[p])[s1+128] =
          make_float2(__uint_as_float(b2.x), __uint_as_float(b2.z));
    }
    if (!ok) s_dead = 1;          // pre-barrier write; benign race
    __syncthreads();              // the only barrier per iteration
    if (s_dead) break;            // uniform post-barrier read -> no divergence
    // ---- compute ----
    const bool act = roleA ? (k < T_STEPS) : (k >= 1);
    if (act) {
      const float4* hp = (roleA || half == 0) ? (const float4*)hbuf0[p]
                                              : (const float4*)hbuf1[p];
      float pr=0.f, pz=0.f, pn=0.f;
#pragma unroll
      for (int i = 0; i < 8; i++) {
        float4 hv = hp[jj + 16*i];   // words 4jj+64i: conflict-free (<=2-way)
        pr += dot4(W[i],hv); pz += dot4(W[8+i],hv); pn += dot4(W[16+i],hv);
      }
      reduce16x3(pr, pz, pn);        // DPP row_ror: full sum in every lane
      if (roleA) {
        if (leadA) {
          float r = fast_sigmoid(igbuf[p][g] + pr);
          float z = fast_sigmoid(igbuf[p][8+g] + pz);
          float n = fast_tanh(igbuf[p][16+g] + r*(pn + bnl));
          float hnew = n + z*(hbuf0[p][eg] - n);
          st_rlx64(&ring0[(size_t)((k+1) & R0M)*HID + eg],
                   pack_tv((unsigned)(k+1), hnew));
          if (k == T_STEPS-1) d_out[T_STEPS + eg] = hnew;
        }
      } else {
        // harvest hh-half sums (lane 16 of the 32-lane group)
        float qr = __shfl(pr, 16, 32);
        float qz = __shfl(pz, 16, 32);
        float qn = __shfl(pn, 16, 32);
        if (leadB) {
          float r = fast_sigmoid(pr + cr + qr);
          float z = fast_sigmoid(pz + cz + qz);
          float n = fast_tanh(pn + cn + r*(qn + bnl));
          float hnew = n + z*(hbuf1[p][eg] - n);
          st_rlx64(&ring1[(size_t)(k & R1M)*HID + eg],
                   pack_tv((unsigned)k, hnew));
          h1a[(size_t)(k-1)*HID + eg] = hnew;   // plain store for the MLP
          if (k == T_STEPS) d_out[T_STEPS + HID + eg] = hnew;
        }
      }
    }
    if (tid < 24) igbuf[p ^ 1][tid] = igpre;
  }
}

// ---- k4: batched MLP head --------------------------------------------------
__global__ __launch_bounds__(64) void mlp_kernel(
    const float* __restrict__ h1_all, const float* __restrict__ mw0,
    const float* __restrict__ mb0, const float* __restrict__ mw1,
    const float* __restrict__ mb1, const float* __restrict__ mw2,
    const float* __restrict__ mb2, float* __restrict__ out) {
  const int l = threadIdx.x;
  const int t0 = blockIdx.x * 8;
  __shared__ float v0s[8][64];
  float acc[8];
#pragma unroll
  for (int tt = 0; tt < 8; tt++) acc[tt] = mb0[l];
  const float4* w = (const float4*)(mw0 + (size_t)l*512);
#pragma unroll 4
  for (int i = 0; i < 128; i++) {
    float4 a = w[i];
#pragma unroll
    for (int tt = 0; tt < 8; tt++) {
      float4 b = ((const float4*)(h1_all + (size_t)(t0+tt)*512))[i];
      acc[tt] = fmaf(a.x,b.x, fmaf(a.y,b.y, fmaf(a.z,b.z, fmaf(a.w,b.w, acc[tt]))));
    }
  }
#pragma unroll
  for (int tt = 0; tt < 8; tt++) v0s[tt][l] = fmaxf(acc[tt], 0.f);
  __syncthreads();
  float acc1[8];
#pragma unroll
  for (int tt = 0; tt < 8; tt++) acc1[tt] = mb1[l];
  const float* w1 = mw1 + (size_t)l*64;
  for (int jj = 0; jj < 64; jj++) {
    float wv = w1[jj];
#pragma unroll
    for (int tt = 0; tt < 8; tt++) acc1[tt] = fmaf(wv, v0s[tt][jj], acc1[tt]);
  }
  float w2 = mw2[l];
  float bb = mb2[0];
#pragma unroll
  for (int tt = 0; tt < 8; tt++) {
    float y = w2 * fmaxf(acc1[tt], 0.f);
#pragma unroll
    for (int s = 32; s > 0; s >>= 1) y += __shfl_down(y, s, 64);
    if (l == 0) out[t0+tt] = y + bb;
  }
}

// ---------------------------------------------------------------------------
extern "C" void kernel_launch(void* const* d_in, const int* in_sizes, int n_in,
                              void* d_out, int out_size, void* d_ws, size_t ws_size,
                              hipStream_t stream) {
  const float* p0  = (const float*)d_in[0];
  const float* p1  = (const float*)d_in[1];
  const float* p2  = (const float*)d_in[2];
  const float* p3  = (const float*)d_in[3];
  const float* p4  = (const float*)d_in[4];
  const float* p5  = (const float*)d_in[5];
  const float* p6  = (const float*)d_in[6];
  const float* p7  = (const float*)d_in[7];
  const float* p8  = (const float*)d_in[8];
  const float* p9  = (const float*)d_in[9];
  const float* p10 = (const float*)d_in[10];
  const float* p11 = (const float*)d_in[11];
  const float* p12 = (const float*)d_in[12];
  const float* hid   = (const float*)d_in[13];
  const float* w_ih0 = (const float*)d_in[14];
  const float* w_hh0 = (const float*)d_in[15];
  const float* b_ih0 = (const float*)d_in[16];
  const float* b_n0  = (const float*)d_in[17];
  const float* w_ih1 = (const float*)d_in[18];
  const float* w_hh1 = (const float*)d_in[19];
  const float* b_ih1 = (const float*)d_in[20];
  const float* b_n1  = (const float*)d_in[21];
  const float* mw0 = (const float*)d_in[22];
  const float* mb0 = (const float*)d_in[23];
  const float* mw1 = (const float*)d_in[24];
  const float* mb1 = (const float*)d_in[25];
  const float* mw2 = (const float*)d_in[26];
  const float* mb2 = (const float*)d_in[27];
  float* out = (float*)d_out;

  // workspace: ig0 | ring0 | ring1 | h1a | [ctrl]  (obs/wT alias h1a region)
  char* base = (char*)d_ws;
  const size_t IG0_B = (size_t)T_STEPS*G3*4;     // 100,663,296
  const size_t R0_B  = (size_t)16*HID*8;         //      65,536
  const size_t R1_B  = (size_t)16*HID*8;         //      65,536
  const size_t H1A_B = (size_t)T_STEPS*HID*4;    //  33,554,432
  const size_t TOTAL = IG0_B + R0_B + R1_B + H1A_B;
  float* ig0 = (float*)base;
  unsigned long long* ring0 = (unsigned long long*)(base + IG0_B);
  unsigned long long* ring1 = (unsigned long long*)(base + IG0_B + R0_B);
  float* h1a = (float*)(base + IG0_B + R0_B + R1_B);
  float* obs = h1a;                                              // alias
  float* wT  = (float*)((char*)h1a + (size_t)T_STEPS*IN_DIM*4);  // alias
  if (ws_size < TOTAL) return;
  int* ctrl = (ws_size >= TOTAL + 4096) ? (int*)(base + TOTAL) : nullptr;

  concat_kernel<<<T_STEPS, 384, 0, stream>>>(p0,p1,p2,p3,p4,p5,p6,p7,p8,p9,p10,p11,p12, obs);
  transpose_kernel<<<dim3(11,48), dim3(32,8), 0, stream>>>(w_ih0, wT);
  ig0_kernel<<<dim3(6, T_STEPS/TTILE), 256, 0, stream>>>(wT, obs, b_ih0, ig0);
  init_kernel<<<1, 512, 0, stream>>>(hid, ring0, ring1, ctrl);
  seq_kernel<<<64, 384, 0, stream>>>(ig0, w_hh0, b_n0, w_ih1, w_hh1, b_ih1, b_n1,
                                     ring0, ring1, h1a, out, ctrl);
  mlp_kernel<<<T_STEPS/8, 64, 0, stream>>>(h1a, mw0, mb0, mw1, mb1, mw2, mb2, out);
}

// Round 9
// 27581.363 us; speedup vs baseline: 1.8480x; 1.0492x over previous
//
#include <hip/hip_runtime.h>
#include <math.h>

// ---------------------------------------------------------------------------
// DefaultHumanoidGRUCritic on MI355X — round 18: REVERT TO BEST (r10 exact)
//
// Eight-round ledger: r10 (27.6ms) is bracketed as the optimum.
//   32WG +6.4ms / 128WG +18.9ms (comm flat below 64, worse above);
//   paired-probe poll +2.5ms; publish drain regressed (wave-scalar stall);
//   wave specialization +23ms (staged data doesn't exist until computed);
//   split WG families -> unbounded skew -> wrong; staging reassignment
//   +1.3ms (barrier = global max over all 512 ring entries, invariant to
//   who stages what; joint 2-line waits fatten the per-lane tail).
// Floor arithmetic: per-iter = publish->LLC-visible + forced-miss discovery
// (~1.1us) + compute/barrier (~0.5us). h-state + 9MB weights cannot fit one
// CU -> every step is a cross-CU broadcast through the chip coherence point
// (XCD L2s non-coherent; no XCD scope in HIP). 16384 sequential LLC rounds
// ~= 18ms hard floor; r10 runs 26ms of seq and 7 attacks on the gap all
// regressed (discovery quantization + slowest-publisher tail = LLC latency).
// This file is the r10 kernel byte-for-byte (comments aside).
// ---------------------------------------------------------------------------

#define T_STEPS 16384
#define IN_DIM 341
#define HID 512
#define G3 1536
#define TTILE 16
#define R0 16
#define R0M (R0-1)
#define R1 16
#define R1M (R1-1)

typedef unsigned int v4u __attribute__((ext_vector_type(4)));

__device__ __forceinline__ float dot4(float4 a, float4 b) {
  return fmaf(a.x, b.x, fmaf(a.y, b.y, fmaf(a.z, b.z, a.w * b.w)));
}
__device__ __forceinline__ float fast_sigmoid(float x) {
  return __builtin_amdgcn_rcpf(1.0f + __expf(-x));
}
__device__ __forceinline__ float fast_tanh(float x) {
  return fmaf(-2.0f, __builtin_amdgcn_rcpf(1.0f + __expf(2.0f * x)), 1.0f);
}
__device__ __forceinline__ void st_rlx64(unsigned long long* p, unsigned long long v) {
  __hip_atomic_store(p, v, __ATOMIC_RELAXED, __HIP_MEMORY_SCOPE_AGENT);
}
__device__ __forceinline__ unsigned long long pack_tv(unsigned tag, float v) {
  return ((unsigned long long)tag << 32) | (unsigned long long)__float_as_uint(v);
}
__device__ __forceinline__ void pin4(float4& v) {
  asm volatile("" : "+v"(v.x), "+v"(v.y), "+v"(v.z), "+v"(v.w));
}
// coherence-point 16B load: two (val,tag) pairs. sc0 sc1 = system-scope load
// semantics on gfx940+ (forced miss to the coherence point); each 8B half is
// written by an 8B atomic store and is tag-verified independently by callers.
__device__ __forceinline__ v4u ld16(const unsigned long long* p) {
  v4u r;
  asm volatile("global_load_dwordx4 %0, %1, off sc0 sc1\n\ts_waitcnt vmcnt(0)"
               : "=v"(r) : "v"(p) : "memory");
  return r;
}
__device__ __forceinline__ void ld16x2(const unsigned long long* p0,
                                       const unsigned long long* p1,
                                       v4u& a, v4u& b) {
  asm volatile("global_load_dwordx4 %0, %2, off sc0 sc1\n\t"
               "global_load_dwordx4 %1, %3, off sc0 sc1\n\t"
               "s_waitcnt vmcnt(0)"
               : "=&v"(a), "=&v"(b) : "v"(p0), "v"(p1) : "memory");
}

// ---- k0: concat observations ----------------------------------------------
__global__ __launch_bounds__(384) void concat_kernel(
    const float* __restrict__ p0, const float* __restrict__ p1,
    const float* __restrict__ p2, const float* __restrict__ p3,
    const float* __restrict__ p4, const float* __restrict__ p5,
    const float* __restrict__ p6, const float* __restrict__ p7,
    const float* __restrict__ p8, const float* __restrict__ p9,
    const float* __restrict__ p10, const float* __restrict__ p11,
    const float* __restrict__ p12, float* __restrict__ obs) {
  int t = blockIdx.x;
  int k = threadIdx.x;
  if (k >= IN_DIM) return;
  float v;
  if (k < 21)       v = p0[t*21 + k];
  else if (k < 42)  v = p1[t*21 + (k-21)];
  else if (k < 202) v = p2[t*160 + (k-42)];
  else if (k < 298) v = p3[t*96 + (k-202)];
  else if (k < 301) v = p4[t*3 + (k-298)];
  else if (k < 304) v = p5[t*3 + (k-301)];
  else if (k < 325) v = p6[t*21 + (k-304)];
  else if (k < 328) v = p7[t*3 + (k-325)];
  else if (k < 332) v = p8[t*4 + (k-328)];
  else if (k < 335) v = p9[t*3 + (k-332)];
  else if (k < 338) v = p10[t*3 + (k-335)];
  else if (k < 340) v = p11[t*2 + (k-338)];
  else              v = p12[t];
  obs[(size_t)t*IN_DIM + k] = v;
}

// ---- k1: transpose w_ih0 ---------------------------------------------------
__global__ __launch_bounds__(256) void transpose_kernel(const float* __restrict__ w,
                                                        float* __restrict__ wT) {
  __shared__ float tile[32][33];
  int tx = threadIdx.x;  // 32
  int ty = threadIdx.y;  // 8
  int k = blockIdx.x*32 + tx;
#pragma unroll
  for (int jj = 0; jj < 4; jj++) {
    int r = blockIdx.y*32 + ty*4 + jj;
    tile[ty*4+jj][tx] = (k < IN_DIM) ? w[(size_t)r*IN_DIM + k] : 0.f;
  }
  __syncthreads();
#pragma unroll
  for (int jj = 0; jj < 4; jj++) {
    int kk = blockIdx.x*32 + ty*4 + jj;
    if (kk < IN_DIM) wT[(size_t)kk*G3 + blockIdx.y*32 + tx] = tile[tx][ty*4+jj];
  }
}

// ---- k2: IG0 = obs @ w_ih0^T + b_ih0 --------------------------------------
__global__ __launch_bounds__(256) void ig0_kernel(const float* __restrict__ wT,
                                                  const float* __restrict__ obs,
                                                  const float* __restrict__ b_ih0,
                                                  float* __restrict__ ig0) {
  int o = blockIdx.x*256 + threadIdx.x;
  int t0 = blockIdx.y * TTILE;
  float acc[TTILE];
  float b = b_ih0[o];
#pragma unroll
  for (int tt = 0; tt < TTILE; tt++) acc[tt] = b;
  for (int k = 0; k < IN_DIM; k++) {
    float wv = wT[(size_t)k*G3 + o];
#pragma unroll
    for (int tt = 0; tt < TTILE; tt++)
      acc[tt] = fmaf(obs[(size_t)(t0+tt)*IN_DIM + k], wv, acc[tt]);
  }
#pragma unroll
  for (int tt = 0; tt < TTILE; tt++)
    ig0[(size_t)(t0+tt)*G3 + o] = acc[tt];
}

// ---- k_init: seed ring slot 0 with tagged initial hidden -------------------
__global__ __launch_bounds__(512) void init_kernel(const float* __restrict__ hid,
                                                   unsigned long long* ring0,
                                                   unsigned long long* ring1) {
  int e = threadIdx.x;
  st_rlx64(&ring0[e], pack_tv(0u, hid[e]));
  st_rlx64(&ring1[e], pack_tv(0u, hid[HID + e]));
}

// ---- k3: fused sequential GRU scan ----------------------------------------
// 64 WGs x 384 threads, 1 block/CU. Iteration k (k = 0..T inclusive):
//   stage h0[k-1] (ring0 slot k&15, tag k) and h1[k-2] (ring1 slot (k-1)&15,
//   tag k-1); compute h0[k] (tid<128, if k<T) and h1[k-1] (tid>=128, if k>=1);
//   publish h0[k] -> ring0 slot (k+1)&15 tag k+1, h1[k-1] -> ring1 slot k&15
//   tag k. Convention: h^(t) lives at slot (t+1)&M with tag t+1; initial
//   hidden seeded at slot 0 tag 0.
__global__ __launch_bounds__(384)
__attribute__((amdgpu_waves_per_eu(1, 2)))
void seq_kernel(
    const float* __restrict__ ig0, const float* __restrict__ w_hh0,
    const float* __restrict__ b_n0, const float* __restrict__ w_ih1,
    const float* __restrict__ w_hh1, const float* __restrict__ b_ih1,
    const float* __restrict__ b_n1,
    unsigned long long* ring0, unsigned long long* ring1,
    float* __restrict__ h1a, float* __restrict__ d_out) {
  __shared__ float hbuf0[2][HID];
  __shared__ float hbuf1[2][HID];
  __shared__ float igbuf[2][24];
  __shared__ float vpad[24576];   // 96KB: occupancy calc -> 1 block/CU
  const int tid = threadIdx.x;
  const int wg = blockIdx.x;
  if (d_out == nullptr) {         // never true; defeats LDS elision
    vpad[tid] = (float)tid;
    __syncthreads();
    h1a[tid] = vpad[383 - tid];
  }

  const bool roleA = (tid < 128);          // 8 h0 elements, 16 lanes each
  const int u = tid - 128;                 // role B: 8 h1 elements, 32 lanes
  const int g = roleA ? (tid >> 4) : (u >> 5);
  const int jj = roleA ? (tid & 15) : (u & 15);
  const int half = roleA ? 0 : ((u >> 4) & 1);   // B: 0=ih(h0), 1=hh(h1)
  const int j32 = roleA ? 0 : (u & 31);
  const int eg = wg*8 + g;
  const bool leadA = roleA && (jj == 0);
  const bool leadB = (!roleA) && (j32 == 0);

  // 24 float4 (96 floats) of weights per lane, loaded once, PINNED resident.
  const float* wsrc = roleA ? w_hh0 : (half ? w_hh1 : w_ih1);
  float4 W[24];
#pragma unroll
  for (int gate = 0; gate < 3; gate++) {
    const float4* row = (const float4*)(wsrc + (size_t)(gate*HID + eg)*HID);
#pragma unroll
    for (int i = 0; i < 8; i++) {
      W[gate*8+i] = row[jj + 16*i];
      pin4(W[gate*8+i]);
    }
  }
  float cr=0.f, cz=0.f, cn=0.f, bnl;
  if (roleA) {
    bnl = b_n0[eg];
  } else {
    cr = b_ih1[eg]; cz = b_ih1[512+eg]; cn = b_ih1[1024+eg]; bnl = b_n1[eg];
  }

  const int iggate = tid >> 3, ige = tid & 7;   // tid<24: ig prefetch lanes
  if (tid < 24) igbuf[0][tid] = ig0[(size_t)iggate*HID + wg*8 + ige];

  for (int k = 0; k <= T_STEPS; k++) {
    const int p = k & 1;
    // prefetch ig for h0[k+1] (plain cached load; LDS write after barrier)
    float igpre = 0.f;
    if (tid < 24) {
      int kk = (k+1 < T_STEPS) ? (k+1) : (T_STEPS-1);
      igpre = ig0[(size_t)kk*G3 + (size_t)iggate*HID + wg*8 + ige];
    }
    // ---- staging: 16B loads, 2 tag-verified pairs each ----
    const unsigned wk0 = (unsigned)k, wk1 = (unsigned)(k-1);
    if (k == 0) {
      if (tid < 256) {
        const unsigned long long* pa = ring0 + 2*tid;
        v4u a = ld16(pa);
        while (a.y != wk0 || a.w != wk0) { __builtin_amdgcn_s_sleep(1); a = ld16(pa); }
        ((float2*)hbuf0[p])[tid] =
            make_float2(__uint_as_float(a.x), __uint_as_float(a.z));
      }
    } else {
      const unsigned long long* pa = ring0 + (size_t)(k & R0M)*HID + 2*tid;
      const unsigned long long* pb = ring1 + (size_t)((k-1) & R1M)*HID + 2*(tid-128);
      if (tid < 128) {
        v4u a = ld16(pa);
        while (a.y != wk0 || a.w != wk0) { __builtin_amdgcn_s_sleep(1); a = ld16(pa); }
        ((float2*)hbuf0[p])[tid] =
            make_float2(__uint_as_float(a.x), __uint_as_float(a.z));
      } else if (tid < 256) {
        v4u a, b;
        ld16x2(pa, pb, a, b);   // both probes in flight together
        while (a.y != wk0 || a.w != wk0) { __builtin_amdgcn_s_sleep(1); a = ld16(pa); }
        while (b.y != wk1 || b.w != wk1) { __builtin_amdgcn_s_sleep(1); b = ld16(pb); }
        ((float2*)hbuf0[p])[tid] =
            make_float2(__uint_as_float(a.x), __uint_as_float(a.z));
        ((float2*)hbuf1[p])[tid-128] =
            make_float2(__uint_as_float(b.x), __uint_as_float(b.z));
      } else {
        v4u b = ld16(pb);
        while (b.y != wk1 || b.w != wk1) { __builtin_amdgcn_s_sleep(1); b = ld16(pb); }
        ((float2*)hbuf1[p])[tid-128] =
            make_float2(__uint_as_float(b.x), __uint_as_float(b.z));
      }
    }
    __syncthreads();   // the only barrier per iteration
    // ---- compute ----
    const bool act = roleA ? (k < T_STEPS) : (k >= 1);
    if (act) {
      const float4* hp = (roleA || half == 0) ? (const float4*)hbuf0[p]
                                              : (const float4*)hbuf1[p];
      float pr=0.f, pz=0.f, pn=0.f;
#pragma unroll
      for (int i = 0; i < 8; i++) {
        float4 hv = hp[jj + 16*i];   // words 4jj+64i: conflict-free (<=2-way)
        pr += dot4(W[i],hv); pz += dot4(W[8+i],hv); pn += dot4(W[16+i],hv);
      }
#pragma unroll
      for (int s = 1; s < 16; s <<= 1) {
        pr += __shfl_xor(pr, s, 16);
        pz += __shfl_xor(pz, s, 16);
        pn += __shfl_xor(pn, s, 16);
      }
      if (roleA) {
        if (leadA) {
          float r = fast_sigmoid(igbuf[p][g] + pr);
          float z = fast_sigmoid(igbuf[p][8+g] + pz);
          float n = fast_tanh(igbuf[p][16+g] + r*(pn + bnl));
          float hnew = n + z*(hbuf0[p][eg] - n);
          st_rlx64(&ring0[(size_t)((k+1) & R0M)*HID + eg],
                   pack_tv((unsigned)(k+1), hnew));
          if (k == T_STEPS-1) d_out[T_STEPS + eg] = hnew;
        }
      } else {
        // harvest hh-half sums (lane 16 of the 32-lane group)
        float qr = __shfl(pr, 16, 32);
        float qz = __shfl(pz, 16, 32);
        float qn = __shfl(pn, 16, 32);
        if (leadB) {
          float r = fast_sigmoid(pr + cr + qr);
          float z = fast_sigmoid(pz + cz + qz);
          float n = fast_tanh(pn + cn + r*(qn + bnl));
          float hnew = n + z*(hbuf1[p][eg] - n);
          st_rlx64(&ring1[(size_t)(k & R1M)*HID + eg],
                   pack_tv((unsigned)k, hnew));
          h1a[(size_t)(k-1)*HID + eg] = hnew;   // plain store for the MLP
          if (k == T_STEPS) d_out[T_STEPS + HID + eg] = hnew;
        }
      }
    }
    if (tid < 24) igbuf[p ^ 1][tid] = igpre;
  }
}

// ---- k4: batched MLP head --------------------------------------------------
__global__ __launch_bounds__(64) void mlp_kernel(
    const float* __restrict__ h1_all, const float* __restrict__ mw0,
    const float* __restrict__ mb0, const float* __restrict__ mw1,
    const float* __restrict__ mb1, const float* __restrict__ mw2,
    const float* __restrict__ mb2, float* __restrict__ out) {
  const int l = threadIdx.x;
  const int t0 = blockIdx.x * 8;
  __shared__ float v0s[8][64];
  float acc[8];
#pragma unroll
  for (int tt = 0; tt < 8; tt++) acc[tt] = mb0[l];
  const float4* w = (const float4*)(mw0 + (size_t)l*512);
#pragma unroll 4
  for (int i = 0; i < 128; i++) {
    float4 a = w[i];
#pragma unroll
    for (int tt = 0; tt < 8; tt++) {
      float4 b = ((const float4*)(h1_all + (size_t)(t0+tt)*512))[i];
      acc[tt] = fmaf(a.x,b.x, fmaf(a.y,b.y, fmaf(a.z,b.z, fmaf(a.w,b.w, acc[tt]))));
    }
  }
#pragma unroll
  for (int tt = 0; tt < 8; tt++) v0s[tt][l] = fmaxf(acc[tt], 0.f);
  __syncthreads();
  float acc1[8];
#pragma unroll
  for (int tt = 0; tt < 8; tt++) acc1[tt] = mb1[l];
  const float* w1 = mw1 + (size_t)l*64;
  for (int jj = 0; jj < 64; jj++) {
    float wv = w1[jj];
#pragma unroll
    for (int tt = 0; tt < 8; tt++) acc1[tt] = fmaf(wv, v0s[tt][jj], acc1[tt]);
  }
  float w2 = mw2[l];
  float bb = mb2[0];
#pragma unroll
  for (int tt = 0; tt < 8; tt++) {
    float y = w2 * fmaxf(acc1[tt], 0.f);
#pragma unroll
    for (int s = 32; s > 0; s >>= 1) y += __shfl_down(y, s, 64);
    if (l == 0) out[t0+tt] = y + bb;
  }
}

// ---------------------------------------------------------------------------
extern "C" void kernel_launch(void* const* d_in, const int* in_sizes, int n_in,
                              void* d_out, int out_size, void* d_ws, size_t ws_size,
                              hipStream_t stream) {
  const float* p0  = (const float*)d_in[0];
  const float* p1  = (const float*)d_in[1];
  const float* p2  = (const float*)d_in[2];
  const float* p3  = (const float*)d_in[3];
  const float* p4  = (const float*)d_in[4];
  const float* p5  = (const float*)d_in[5];
  const float* p6  = (const float*)d_in[6];
  const float* p7  = (const float*)d_in[7];
  const float* p8  = (const float*)d_in[8];
  const float* p9  = (const float*)d_in[9];
  const float* p10 = (const float*)d_in[10];
  const float* p11 = (const float*)d_in[11];
  const float* p12 = (const float*)d_in[12];
  const float* hid   = (const float*)d_in[13];
  const float* w_ih0 = (const float*)d_in[14];
  const float* w_hh0 = (const float*)d_in[15];
  const float* b_ih0 = (const float*)d_in[16];
  const float* b_n0  = (const float*)d_in[17];
  const float* w_ih1 = (const float*)d_in[18];
  const float* w_hh1 = (const float*)d_in[19];
  const float* b_ih1 = (const float*)d_in[20];
  const float* b_n1  = (const float*)d_in[21];
  const float* mw0 = (const float*)d_in[22];
  const float* mb0 = (const float*)d_in[23];
  const float* mw1 = (const float*)d_in[24];
  const float* mb1 = (const float*)d_in[25];
  const float* mw2 = (const float*)d_in[26];
  const float* mb2 = (const float*)d_in[27];
  float* out = (float*)d_out;

  // workspace: ig0 | ring0 | ring1 | h1a  (obs/wT alias h1a region)
  char* base = (char*)d_ws;
  const size_t IG0_B = (size_t)T_STEPS*G3*4;     // 100,663,296
  const size_t R0_B  = (size_t)R0*HID*8;         //      65,536
  const size_t R1_B  = (size_t)R1*HID*8;         //      65,536
  const size_t H1A_B = (size_t)T_STEPS*HID*4;    //  33,554,432
  float* ig0 = (float*)base;
  unsigned long long* ring0 = (unsigned long long*)(base + IG0_B);
  unsigned long long* ring1 = (unsigned long long*)(base + IG0_B + R0_B);
  float* h1a = (float*)(base + IG0_B + R0_B + R1_B);
  float* obs = h1a;                                              // alias
  float* wT  = (float*)((char*)h1a + (size_t)T_STEPS*IN_DIM*4);  // alias
  if (ws_size < IG0_B + R0_B + R1_B + H1A_B) return;

  concat_kernel<<<T_STEPS, 384, 0, stream>>>(p0,p1,p2,p3,p4,p5,p6,p7,p8,p9,p10,p11,p12, obs);
  transpose_kernel<<<dim3(11,48), dim3(32,8), 0, stream>>>(w_ih0, wT);
  ig0_kernel<<<dim3(6, T_STEPS/TTILE), 256, 0, stream>>>(wT, obs, b_ih0, ig0);
  init_kernel<<<1, 512, 0, stream>>>(hid, ring0, ring1);
  seq_kernel<<<64, 384, 0, stream>>>(ig0, w_hh0, b_n0, w_ih1, w_hh1, b_ih1, b_n1,
                                     ring0, ring1, h1a, out);
  mlp_kernel<<<T_STEPS/8, 64, 0, stream>>>(h1a, mw0, mb0, mw1, mb1, mw2, mb2, out);
}